// Round 5
// baseline (972.795 us; speedup 1.0000x reference)
//
#include <hip/hip_runtime.h>
#include <cstdint>
#include <cstddef>

// ---------- types / helpers ----------
typedef __attribute__((ext_vector_type(8))) short bf16x8;   // 8 bf16 (4 VGPR)
typedef __attribute__((ext_vector_type(4))) short bf16x4;   // 8 bytes
typedef __attribute__((ext_vector_type(4))) float f32x4;

#define MFMA_BF16 __builtin_amdgcn_mfma_f32_16x16x32_bf16

constexpr int B_   = 4;
constexpr int S_   = 2048;
constexpr int H_   = 2048;
constexpr int C_   = 512;
constexpr int QKD  = 2560;   // H_ + C_
constexpr int NH   = 16;
constexpr int DQK  = 160;    // QKD / NH
constexpr int DV   = 128;    // H_ / NH
constexpr int MTOT = B_ * S_; // 8192

static __device__ __forceinline__ short f2bf(float f) {
  unsigned u = __builtin_bit_cast(unsigned, f);
  u += 0x7FFFu + ((u >> 16) & 1u);           // round-nearest-even
  return (short)(u >> 16);
}
static __device__ __forceinline__ float bf2f(short h) {
  unsigned u = ((unsigned)(unsigned short)h) << 16;
  return __builtin_bit_cast(float, u);
}
static __device__ __forceinline__ unsigned cvt_pk_bf16(float a, float b) {
  unsigned r;
  asm("v_cvt_pk_bf16_f32 %0, %1, %2" : "=v"(r) : "v"(a), "v"(b));
  return r;   // low16 = bf16(a), high16 = bf16(b)
}
static __device__ __forceinline__ void gload_lds16(const void* g, void* l) {
  // async global->LDS, 16B/lane; LDS dest = wave-uniform base + lane*16
  __builtin_amdgcn_global_load_lds((const __attribute__((address_space(1))) unsigned*)g,
                                   (__attribute__((address_space(3))) unsigned*)l, 16, 0, 0);
}

// ---------- elementwise: build qk_in = [hidden | cond] as bf16 ----------
__global__ __launch_bounds__(256) void k_build_qkin(const float* __restrict__ hidden,
                                                    const float* __restrict__ cond,
                                                    short* __restrict__ qk) {
  int i = blockIdx.x * 256 + threadIdx.x;       // one 4-elem chunk of qk_in
  int row = i / (QKD / 4);
  int c4  = i - row * (QKD / 4);
  f32x4 v;
  if (c4 < H_ / 4) v = *((const f32x4*)hidden + (size_t)row * (H_ / 4) + c4);
  else             v = *((const f32x4*)cond   + (size_t)row * (C_ / 4) + (c4 - H_ / 4));
  bf16x4 o;
  o[0] = f2bf(v[0]); o[1] = f2bf(v[1]); o[2] = f2bf(v[2]); o[3] = f2bf(v[3]);
  *(bf16x4*)(qk + (size_t)row * QKD + c4 * 4) = o;
}

// ---------- elementwise: fp32 -> bf16 (weights) ----------
__global__ __launch_bounds__(256) void k_cvt_bf16(const float* __restrict__ in,
                                                  short* __restrict__ out) {
  size_t i = (size_t)blockIdx.x * 256 + threadIdx.x;
  f32x4 v = *((const f32x4*)in + i);
  bf16x4 o;
  o[0] = f2bf(v[0]); o[1] = f2bf(v[1]); o[2] = f2bf(v[2]); o[3] = f2bf(v[3]);
  *(bf16x4*)(out + i * 4) = o;
}

// ---------- GEMM: C = A[M x K](lda) @ W[N x K]^T, bf16 in, fp32 acc ----------
// m97-style: 128x128 tile, BK=32, 4 waves (2x2), global_load_lds staging.
// XCD-chunked block swizzle: consecutive wg2 share the B-panel (L2-resident).
// MODE 0: bf16 head-major [b,h,s,DQK]   (q/k projections, N=QKD)
// MODE 1: bf16 V-transposed [b,h,DV,s]  (v projection, N=H_)
// MODE 2: fp32 row-major [M][N]         (output projection)
template<int MODE>
__global__ __launch_bounds__(256) void k_gemm_bt(const short* __restrict__ A,
                                                 const short* __restrict__ W,
                                                 void* __restrict__ Cp,
                                                 int N, int K, int lda) {
  __shared__ short lA[128 * 32];
  __shared__ short lB[128 * 32];
  const int tid = threadIdx.x;
  const int lane = tid & 63, wid = tid >> 6;
  // bijective XCD-chunked remap (nwg % 8 == 0 for all our grids)
  const int gx = gridDim.x, gy = gridDim.y;
  const int nwg = gx * gy, cpx = nwg >> 3;
  const int wg  = blockIdx.y * gx + blockIdx.x;
  const int wg2 = (wg & 7) * cpx + (wg >> 3);
  const int xb  = wg2 / gy, yb = wg2 - xb * gy;   // consecutive wg2 share xb (B-panel)
  const int m0 = yb * 128, n0 = xb * 128;
  const int wr = wid >> 1, wc = wid & 1;          // wave 64x64 quadrant
  const int l15 = lane & 15, l4 = lane >> 4;
  f32x4 acc[4][4] = {};

  const int srow = lane >> 2;                     // staging: 16 rows/chunk, 4 lanes/row
  const int scol = (lane & 3) * 8;                // 8 bf16 = 16B per lane
  const short* Abase = A + (size_t)m0 * lda;
  const short* Wbase = W + (size_t)n0 * K;
  const int nkt = K >> 5;

  for (int kt = 0; kt < nkt; ++kt) {
    const int k0 = kt << 5;
#pragma unroll
    for (int i = 0; i < 2; ++i) {
      int c = wid * 2 + i;                        // chunks 0..7 each for A and B
      gload_lds16(Abase + (size_t)(c * 16 + srow) * lda + k0 + scol, &lA[c * 512]);
      gload_lds16(Wbase + (size_t)(c * 16 + srow) * K   + k0 + scol, &lB[c * 512]);
    }
    __syncthreads();
    bf16x8 af[4], bv[4];
#pragma unroll
    for (int x = 0; x < 4; ++x) {
      af[x] = *(const bf16x8*)&lA[(wr * 64 + x * 16 + l15) * 32 + l4 * 8];
      bv[x] = *(const bf16x8*)&lB[(wc * 64 + x * 16 + l15) * 32 + l4 * 8];
    }
#pragma unroll
    for (int mi = 0; mi < 4; ++mi)
#pragma unroll
      for (int nj = 0; nj < 4; ++nj)
        acc[mi][nj] = MFMA_BF16(af[mi], bv[nj], acc[mi][nj], 0, 0, 0);
    __syncthreads();
  }

  // epilogue; C frag layout: col = lane&15, row = (lane>>4)*4 + r
#pragma unroll
  for (int mi = 0; mi < 4; ++mi) {
#pragma unroll
    for (int nj = 0; nj < 4; ++nj) {
      int crow = m0 + wr * 64 + mi * 16 + l4 * 4;       // multiple of 4
      int ccol = n0 + wc * 64 + nj * 16 + l15;
      if constexpr (MODE == 0) {
        int b = crow >> 11;                              // block rows share b (128 | 2048)
        int s = crow - (b << 11);
        int h = ccol / DQK;                              // frags never straddle heads (16|160)
        int d = ccol - h * DQK;
        short* dst = (short*)Cp + ((size_t)(b * NH + h) * S_) * DQK + d;
#pragma unroll
        for (int r = 0; r < 4; ++r)
          dst[(size_t)(s + r) * DQK] = f2bf(acc[mi][nj][r]);
      } else if constexpr (MODE == 1) {
        int b = crow >> 11;
        int s = crow - (b << 11);
        int h = ccol >> 7;
        int d = ccol & 127;
        short* dst = (short*)Cp + ((size_t)(b * NH + h) * DV + d) * S_ + s;
        bf16x4 o;
        o[0] = f2bf(acc[mi][nj][0]); o[1] = f2bf(acc[mi][nj][1]);
        o[2] = f2bf(acc[mi][nj][2]); o[3] = f2bf(acc[mi][nj][3]);
        *(bf16x4*)dst = o;                               // 4 consecutive s, 8B store
      } else {
        float* dst = (float*)Cp + (size_t)crow * N + ccol;
#pragma unroll
        for (int r = 0; r < 4; ++r) dst[(size_t)r * N] = acc[mi][nj][r];
      }
    }
  }
}

// ---------- RoPE (in-place on bf16 head-major [bh, s, DQK]) ----------
__global__ __launch_bounds__(256) void k_rope(short* __restrict__ x,
                                              const float* __restrict__ cs,
                                              const float* __restrict__ sn) {
  int i = blockIdx.x * 256 + threadIdx.x;  // total = 64*2048*20 chunks of 4 d's
  int c4   = i % 20;
  int rest = i / 20;
  int s  = rest & (S_ - 1);
  int bh = rest >> 11;
  size_t base = ((size_t)bh * S_ + s) * DQK;
  int d = c4 * 4;
  bf16x4 x1 = *(bf16x4*)(x + base + d);
  bf16x4 x2 = *(bf16x4*)(x + base + d + 80);
  f32x4 c1 = *(const f32x4*)(cs + (size_t)s * DQK + d);
  f32x4 s1 = *(const f32x4*)(sn + (size_t)s * DQK + d);
  f32x4 c2 = *(const f32x4*)(cs + (size_t)s * DQK + d + 80);
  f32x4 s2 = *(const f32x4*)(sn + (size_t)s * DQK + d + 80);
  bf16x4 o1, o2;
#pragma unroll
  for (int j = 0; j < 4; ++j) {
    float a = bf2f(x1[j]), b = bf2f(x2[j]);
    o1[j] = f2bf(a * c1[j] - b * s1[j]);   // d < 80:  x*cos - x[d+80]*sin
    o2[j] = f2bf(b * c2[j] + a * s2[j]);   // d >= 80: x*cos + x[d-80]*sin
  }
  *(bf16x4*)(x + base + d)      = o1;
  *(bf16x4*)(x + base + d + 80) = o2;
}

// ---------- flash attention (pipelined: K dbuf, V late-wait, 1 barrier/tile) ----------
// grid 1024 blocks; 256 threads = 4 waves; wave owns 32 q-rows.
// q,k head-major [bh, s, DQK]; vt [bh, DV, s]; out token-major bf16 [8192, 2048].
__global__ __launch_bounds__(256) void k_attn(const short* __restrict__ q,
                                              const short* __restrict__ k,
                                              const short* __restrict__ vt,
                                              short* __restrict__ attn) {
  __shared__ short lK[2][64 * 160];   // 40KB, rows 320B, two-tier XOR-swizzled, dbuf
  __shared__ short lV[128 * 64];      // 16KB, rows 128B, XOR-swizzled (row&7)<<4
  __shared__ short lP[4][32][40];     // 10KB, per-wave 80B rows (conflict-free), kc-split
  const int tid = threadIdx.x, lane = tid & 63, wid = tid >> 6;
  // XCD-chunked remap: each XCD gets 8 consecutive bh (16 q-blocks each)
  const int wg  = blockIdx.y * gridDim.x + blockIdx.x;       // 0..1023
  const int wg2 = (wg & 7) * 128 + (wg >> 3);
  const int bh  = wg2 >> 4, b = bh >> 4, h = bh & 15;
  const int q0  = (wg2 & 15) * 128;
  const short* Q  = q  + (size_t)bh * S_ * DQK;
  const char*  Kb = (const char*)(k + (size_t)bh * S_ * DQK);
  const char*  Vb = (const char*)(vt + (size_t)bh * DV * S_);
  const int l15 = lane & 15, l4 = lane >> 4;

  // hoist Q fragments to registers (L2-served, once per block)
  bf16x8 qf[2][5];
#pragma unroll
  for (int mi = 0; mi < 2; ++mi)
#pragma unroll
    for (int ks = 0; ks < 5; ++ks)
      qf[mi][ks] = *(const bf16x8*)(Q + (size_t)(q0 + wid * 32 + mi * 16 + l15) * DQK + ks * 32 + l4 * 8);

  f32x4 acc[2][8] = {};
  float mrow[2], lrow[2];
#pragma unroll
  for (int mi = 0; mi < 2; ++mi) { mrow[mi] = -1e30f; lrow[mi] = 0.f; }
  const float csc = 0.07905694150420949f * 1.44269504089f; // 1/sqrt(160) * log2(e)

  // staging address precompute (per-lane, loop-invariant)
  // K: two-tier source XOR so LDS[row][col] = K[row][col ^ swz(row)]
  int koff[5], kcolS[5];
#pragma unroll
  for (int i = 0; i < 5; ++i) {
    int c = wid * 5 + i;
    int off = c * 1024 + lane * 16;
    int row = off / 320;
    int colB = off - row * 320;
    int g = colB >> 4;
    int colS = (g < 16) ? (colB ^ ((row & 7) << 4)) : (colB ^ ((row & 3) << 4));
    koff[i] = row;  kcolS[i] = colS;
  }
  const int vrow = lane >> 3;
  const int vcb  = (lane & 7) ^ vrow;   // V granule xor = (lane&7) ^ (row&7)

  // prologue: stage K tile 0 into buf 0
#pragma unroll
  for (int i = 0; i < 5; ++i)
    gload_lds16(Kb + (size_t)koff[i] * 320 + kcolS[i], &lK[0][(wid * 5 + i) * 512]);
  __syncthreads();

  int cur = 0;
  for (int t = 0; t < 32; ++t, cur ^= 1) {
    const int kv0 = t * 64;
    // stage V[t] (single buffer; consumed late this iteration) — 4 loads/wave
#pragma unroll
    for (int i = 0; i < 4; ++i) {
      int c = wid * 4 + i;
      gload_lds16(Vb + (size_t)(c * 8 + vrow) * (S_ * 2) + kv0 * 2 + vcb * 16, &lV[c * 512]);
    }
    // stage K[t+1] into lK[cur^1] (wrap at end keeps vmcnt count uniform)
    {
      const int kvn = ((t + 1) & 31) * 64;
#pragma unroll
      for (int i = 0; i < 5; ++i)
        gload_lds16(Kb + (size_t)(kvn + koff[i]) * 320 + kcolS[i], &lK[cur ^ 1][(wid * 5 + i) * 512]);
    }

    // swapped QK^T: S^T[64 kv x 32 q] per wave; kv = kj*16 + l4*4 + r, q = mi*16 + l15
    f32x4 sc[4][2] = {};
    __builtin_amdgcn_s_setprio(1);
#pragma unroll
    for (int kj = 0; kj < 4; ++kj) {
      int row = kj * 16 + l15;
      int x7 = (row & 7) << 4, x3 = (row & 3) << 4;
#pragma unroll
      for (int ks = 0; ks < 5; ++ks) {
        int colB = (ks < 4) ? ((ks * 64 + l4 * 16) ^ x7) : ((256 + l4 * 16) ^ x3);
        bf16x8 kf = *(const bf16x8*)((const char*)&lK[cur][0] + row * 320 + colB);
        sc[kj][0] = MFMA_BF16(kf, qf[0][ks], sc[kj][0], 0, 0, 0);
        sc[kj][1] = MFMA_BF16(kf, qf[1][ks], sc[kj][1], 0, 0, 0);
      }
    }
    __builtin_amdgcn_s_setprio(0);

    // online softmax: per-lane q-column; in-lane max16 + 2 shfl; defer-max THR=8
    float pms[2];
#pragma unroll
    for (int mi = 0; mi < 2; ++mi) {
      float mv = sc[0][mi][0];
#pragma unroll
      for (int kj = 0; kj < 4; ++kj)
#pragma unroll
        for (int r = 0; r < 4; ++r) mv = fmaxf(mv, sc[kj][mi][r]);
      mv = fmaxf(mv, __shfl_xor(mv, 16, 64));
      mv = fmaxf(mv, __shfl_xor(mv, 32, 64));
      pms[mi] = mv * csc;
    }
    if (__any((pms[0] > mrow[0] + 8.0f) || (pms[1] > mrow[1] + 8.0f))) {
#pragma unroll
      for (int mi = 0; mi < 2; ++mi) {
        float mn = fmaxf(mrow[mi], pms[mi]);
        float al = exp2f(mrow[mi] - mn);
        mrow[mi] = mn; lrow[mi] *= al;
#pragma unroll
        for (int r = 0; r < 4; ++r) {
          float alr = __shfl(al, (lane & 48) | (l4 * 4 + r), 64);  // al for acc-row q
#pragma unroll
          for (int nf = 0; nf < 8; ++nf) acc[mi][nf][r] *= alr;
        }
      }
    }
    // P = exp2(sc*csc - m); pack pairs into dwords (kept in regs until kc phase)
    uint2 pk[2][4];
#pragma unroll
    for (int mi = 0; mi < 2; ++mi) {
#pragma unroll
      for (int kj = 0; kj < 4; ++kj) {
        float p0 = exp2f(sc[kj][mi][0] * csc - mrow[mi]);
        float p1 = exp2f(sc[kj][mi][1] * csc - mrow[mi]);
        float p2 = exp2f(sc[kj][mi][2] * csc - mrow[mi]);
        float p3 = exp2f(sc[kj][mi][3] * csc - mrow[mi]);
        lrow[mi] += (p0 + p1) + (p2 + p3);
        pk[mi][kj].x = cvt_pk_bf16(p0, p1);
        pk[mi][kj].y = cvt_pk_bf16(p2, p3);
      }
    }

    // PV per kv-half: write P half -> pa read -> MFMA vs lV (B-frag)
    __builtin_amdgcn_s_setprio(1);
#pragma unroll
    for (int kc = 0; kc < 2; ++kc) {
#pragma unroll
      for (int mi = 0; mi < 2; ++mi) {
        int qrow = mi * 16 + l15;
#pragma unroll
        for (int j2 = 0; j2 < 2; ++j2)
          *(uint2*)&lP[wid][qrow][j2 * 16 + l4 * 4] = pk[mi][kc * 2 + j2];
      }
      bf16x8 pa[2];
#pragma unroll
      for (int mi = 0; mi < 2; ++mi)
        pa[mi] = *(const bf16x8*)&lP[wid][mi * 16 + l15][l4 * 8];
      if (kc == 0)  // V's 4 loads are the oldest of 9 outstanding -> done at <=5
        asm volatile("s_waitcnt vmcnt(5)" ::: "memory");
#pragma unroll
      for (int nf = 0; nf < 8; ++nf) {
        int row = nf * 16 + l15;
        bf16x8 vf = *(const bf16x8*)((const char*)lV + row * 128 +
                                     ((kc * 64 + l4 * 16) ^ ((row & 7) << 4)));
        acc[0][nf] = MFMA_BF16(pa[0], vf, acc[0][nf], 0, 0, 0);
        acc[1][nf] = MFMA_BF16(pa[1], vf, acc[1][nf], 0, 0, 0);
      }
    }
    __builtin_amdgcn_s_setprio(0);
    __syncthreads();   // drains K[t+1]; protects lV + lK[cur^1] for next iter
  }

  // finalize: cross-l4 sum, invert, redistribute to acc-row layout, store
  float invr[2][4];
#pragma unroll
  for (int mi = 0; mi < 2; ++mi) {
    float s = lrow[mi];
    s += __shfl_xor(s, 16, 64);
    s += __shfl_xor(s, 32, 64);
    float inv = 1.0f / s;
#pragma unroll
    for (int r = 0; r < 4; ++r)
      invr[mi][r] = __shfl(inv, (lane & 48) | (l4 * 4 + r), 64);
  }
#pragma unroll
  for (int mi = 0; mi < 2; ++mi)
#pragma unroll
    for (int nf = 0; nf < 8; ++nf) {
      size_t col = (size_t)h * DV + nf * 16 + l15;
#pragma unroll
      for (int r = 0; r < 4; ++r) {
        int mg = q0 + wid * 32 + mi * 16 + l4 * 4 + r;
        attn[(size_t)(b * S_ + mg) * H_ + col] = f2bf(acc[mi][nf][r] * invr[mi][r]);
      }
    }
}

// ---------- launcher ----------
extern "C" void kernel_launch(void* const* d_in, const int* in_sizes, int n_in,
                              void* d_out, int out_size, void* d_ws, size_t ws_size,
                              hipStream_t stream) {
  const float* hidden = (const float*)d_in[0];
  const float* cond   = (const float*)d_in[1];
  const float* cosp   = (const float*)d_in[2];
  const float* sinp   = (const float*)d_in[3];
  const float* Wq     = (const float*)d_in[4];
  const float* Wk     = (const float*)d_in[5];
  const float* Wv     = (const float*)d_in[6];
  const float* Wo     = (const float*)d_in[7];

  constexpr size_t SZ_QKIN = (size_t)MTOT * QKD * 2;     // 41,943,040
  constexpr size_t SZ_VT   = (size_t)MTOT * H_ * 2;      // 33,554,432
  constexpr size_t SZ_WBF  = (size_t)QKD * QKD * 2;      // 13,107,200
  constexpr size_t WS_NEED = SZ_QKIN * 3 + SZ_VT + SZ_WBF;
  if (ws_size < WS_NEED) return;   // defensive: never write OOB scratch

  char* ws = (char*)d_ws;
  short* qk_in = (short*)(ws);
  short* qbuf  = (short*)(ws + SZ_QKIN);
  short* kbuf  = (short*)(ws + 2 * SZ_QKIN);
  short* vtbuf = (short*)(ws + 3 * SZ_QKIN);
  short* w_bf  = (short*)(ws + 3 * SZ_QKIN + SZ_VT);
  short* attn  = qk_in;                      // alias: qk_in dead after v-projection
  float* outp  = (float*)d_out;

  k_build_qkin<<<(MTOT * QKD / 4) / 256, 256, 0, stream>>>(hidden, cond, qk_in);

  dim3 gq(QKD / 128, MTOT / 128);   // (20, 64)
  dim3 gv(H_ / 128, MTOT / 128);    // (16, 64)

  k_cvt_bf16<<<(QKD * QKD / 4) / 256, 256, 0, stream>>>(Wq, w_bf);
  k_gemm_bt<0><<<gq, 256, 0, stream>>>(qk_in, w_bf, qbuf, QKD, QKD, QKD);

  k_cvt_bf16<<<(QKD * QKD / 4) / 256, 256, 0, stream>>>(Wk, w_bf);
  k_gemm_bt<0><<<gq, 256, 0, stream>>>(qk_in, w_bf, kbuf, QKD, QKD, QKD);

  k_cvt_bf16<<<(H_ * H_ / 4) / 256, 256, 0, stream>>>(Wv, w_bf);
  k_gemm_bt<1><<<gv, 256, 0, stream>>>(qk_in, w_bf, vtbuf, H_, H_, QKD);

  k_rope<<<(B_ * NH * S_ * 20) / 256, 256, 0, stream>>>(qbuf, cosp, sinp);
  k_rope<<<(B_ * NH * S_ * 20) / 256, 256, 0, stream>>>(kbuf, cosp, sinp);

  dim3 ga(S_ / 128, B_ * NH);       // (16, 64)
  k_attn<<<ga, 256, 0, stream>>>(qbuf, kbuf, vtbuf, attn);

  k_cvt_bf16<<<(H_ * H_ / 4) / 256, 256, 0, stream>>>(Wo, w_bf);
  k_gemm_bt<2><<<gv, 256, 0, stream>>>(attn, w_bf, outp, H_, H_, H_);
}

// Round 6
// 871.599 us; speedup vs baseline: 1.1161x; 1.1161x over previous
//
#include <hip/hip_runtime.h>
#include <cstdint>
#include <cstddef>

// ---------- types / helpers ----------
typedef __attribute__((ext_vector_type(8))) short bf16x8;   // 8 bf16 (4 VGPR)
typedef __attribute__((ext_vector_type(4))) short bf16x4;   // 8 bytes
typedef __attribute__((ext_vector_type(4))) float f32x4;

#define MFMA_BF16 __builtin_amdgcn_mfma_f32_16x16x32_bf16

constexpr int B_   = 4;
constexpr int S_   = 2048;
constexpr int H_   = 2048;
constexpr int C_   = 512;
constexpr int QKD  = 2560;   // H_ + C_
constexpr int NH   = 16;
constexpr int DQK  = 160;    // QKD / NH
constexpr int DV   = 128;    // H_ / NH
constexpr int MTOT = B_ * S_; // 8192

static __device__ __forceinline__ short f2bf(float f) {
  unsigned u = __builtin_bit_cast(unsigned, f);
  u += 0x7FFFu + ((u >> 16) & 1u);           // round-nearest-even
  return (short)(u >> 16);
}
static __device__ __forceinline__ float bf2f(short h) {
  unsigned u = ((unsigned)(unsigned short)h) << 16;
  return __builtin_bit_cast(float, u);
}
static __device__ __forceinline__ unsigned cvt_pk_bf16(float a, float b) {
  unsigned r;
  asm("v_cvt_pk_bf16_f32 %0, %1, %2" : "=v"(r) : "v"(a), "v"(b));
  return r;   // low16 = bf16(a), high16 = bf16(b)
}
static __device__ __forceinline__ void gload_lds16(const void* g, void* l) {
  // async global->LDS, 16B/lane; LDS dest = wave-uniform base + lane*16
  __builtin_amdgcn_global_load_lds((const __attribute__((address_space(1))) unsigned*)g,
                                   (__attribute__((address_space(3))) unsigned*)l, 16, 0, 0);
}

// ---------- elementwise: build qk_in = [hidden | cond] as bf16 ----------
__global__ __launch_bounds__(256) void k_build_qkin(const float* __restrict__ hidden,
                                                    const float* __restrict__ cond,
                                                    short* __restrict__ qk) {
  int i = blockIdx.x * 256 + threadIdx.x;       // one 4-elem chunk of qk_in
  int row = i / (QKD / 4);
  int c4  = i - row * (QKD / 4);
  f32x4 v;
  if (c4 < H_ / 4) v = *((const f32x4*)hidden + (size_t)row * (H_ / 4) + c4);
  else             v = *((const f32x4*)cond   + (size_t)row * (C_ / 4) + (c4 - H_ / 4));
  bf16x4 o;
  o[0] = f2bf(v[0]); o[1] = f2bf(v[1]); o[2] = f2bf(v[2]); o[3] = f2bf(v[3]);
  *(bf16x4*)(qk + (size_t)row * QKD + c4 * 4) = o;
}

// ---------- elementwise: fp32 -> bf16 (weights) ----------
__global__ __launch_bounds__(256) void k_cvt_bf16(const float* __restrict__ in,
                                                  short* __restrict__ out) {
  size_t i = (size_t)blockIdx.x * 256 + threadIdx.x;
  f32x4 v = *((const f32x4*)in + i);
  bf16x4 o;
  o[0] = f2bf(v[0]); o[1] = f2bf(v[1]); o[2] = f2bf(v[2]); o[3] = f2bf(v[3]);
  *(bf16x4*)(out + i * 4) = o;
}

// ---------- GEMM: C = A[M x K](lda) @ W[N x K]^T, bf16 in, fp32 acc ----------
// m97-style: 128x128 tile, BK=32, 4 waves (2x2), global_load_lds staging.
// XCD-chunked block swizzle: consecutive wg2 share the B-panel (L2-resident).
// MODE 0: bf16 head-major [b,h,s,DQK]   (q/k projections, N=QKD)
// MODE 1: bf16 V-transposed [b,h,DV,s]  (v projection, N=H_)
// MODE 2: fp32 row-major [M][N]         (output projection)
template<int MODE>
__global__ __launch_bounds__(256) void k_gemm_bt(const short* __restrict__ A,
                                                 const short* __restrict__ W,
                                                 void* __restrict__ Cp,
                                                 int N, int K, int lda) {
  __shared__ short lA[128 * 32];
  __shared__ short lB[128 * 32];
  const int tid = threadIdx.x;
  const int lane = tid & 63, wid = tid >> 6;
  // bijective XCD-chunked remap (nwg % 8 == 0 for all our grids)
  const int gx = gridDim.x, gy = gridDim.y;
  const int nwg = gx * gy, cpx = nwg >> 3;
  const int wg  = blockIdx.y * gx + blockIdx.x;
  const int wg2 = (wg & 7) * cpx + (wg >> 3);
  const int xb  = wg2 / gy, yb = wg2 - xb * gy;   // consecutive wg2 share xb (B-panel)
  const int m0 = yb * 128, n0 = xb * 128;
  const int wr = wid >> 1, wc = wid & 1;          // wave 64x64 quadrant
  const int l15 = lane & 15, l4 = lane >> 4;
  f32x4 acc[4][4] = {};

  const int srow = lane >> 2;                     // staging: 16 rows/chunk, 4 lanes/row
  const int scol = (lane & 3) * 8;                // 8 bf16 = 16B per lane
  const short* Abase = A + (size_t)m0 * lda;
  const short* Wbase = W + (size_t)n0 * K;
  const int nkt = K >> 5;

  for (int kt = 0; kt < nkt; ++kt) {
    const int k0 = kt << 5;
#pragma unroll
    for (int i = 0; i < 2; ++i) {
      int c = wid * 2 + i;                        // chunks 0..7 each for A and B
      gload_lds16(Abase + (size_t)(c * 16 + srow) * lda + k0 + scol, &lA[c * 512]);
      gload_lds16(Wbase + (size_t)(c * 16 + srow) * K   + k0 + scol, &lB[c * 512]);
    }
    __syncthreads();
    bf16x8 af[4], bv[4];
#pragma unroll
    for (int x = 0; x < 4; ++x) {
      af[x] = *(const bf16x8*)&lA[(wr * 64 + x * 16 + l15) * 32 + l4 * 8];
      bv[x] = *(const bf16x8*)&lB[(wc * 64 + x * 16 + l15) * 32 + l4 * 8];
    }
#pragma unroll
    for (int mi = 0; mi < 4; ++mi)
#pragma unroll
      for (int nj = 0; nj < 4; ++nj)
        acc[mi][nj] = MFMA_BF16(af[mi], bv[nj], acc[mi][nj], 0, 0, 0);
    __syncthreads();
  }

  // epilogue; C frag layout: col = lane&15, row = (lane>>4)*4 + r
#pragma unroll
  for (int mi = 0; mi < 4; ++mi) {
#pragma unroll
    for (int nj = 0; nj < 4; ++nj) {
      int crow = m0 + wr * 64 + mi * 16 + l4 * 4;       // multiple of 4
      int ccol = n0 + wc * 64 + nj * 16 + l15;
      if constexpr (MODE == 0) {
        int b = crow >> 11;                              // block rows share b (128 | 2048)
        int s = crow - (b << 11);
        int h = ccol / DQK;                              // frags never straddle heads (16|160)
        int d = ccol - h * DQK;
        short* dst = (short*)Cp + ((size_t)(b * NH + h) * S_) * DQK + d;
#pragma unroll
        for (int r = 0; r < 4; ++r)
          dst[(size_t)(s + r) * DQK] = f2bf(acc[mi][nj][r]);
      } else if constexpr (MODE == 1) {
        int b = crow >> 11;
        int s = crow - (b << 11);
        int h = ccol >> 7;
        int d = ccol & 127;
        short* dst = (short*)Cp + ((size_t)(b * NH + h) * DV + d) * S_ + s;
        bf16x4 o;
        o[0] = f2bf(acc[mi][nj][0]); o[1] = f2bf(acc[mi][nj][1]);
        o[2] = f2bf(acc[mi][nj][2]); o[3] = f2bf(acc[mi][nj][3]);
        *(bf16x4*)dst = o;                               // 4 consecutive s, 8B store
      } else {
        float* dst = (float*)Cp + (size_t)crow * N + ccol;
#pragma unroll
        for (int r = 0; r < 4; ++r) dst[(size_t)r * N] = acc[mi][nj][r];
      }
    }
  }
}

// ---------- RoPE (in-place on bf16 head-major [bh, s, DQK]) ----------
__global__ __launch_bounds__(256) void k_rope(short* __restrict__ x,
                                              const float* __restrict__ cs,
                                              const float* __restrict__ sn) {
  int i = blockIdx.x * 256 + threadIdx.x;  // total = 64*2048*20 chunks of 4 d's
  int c4   = i % 20;
  int rest = i / 20;
  int s  = rest & (S_ - 1);
  int bh = rest >> 11;
  size_t base = ((size_t)bh * S_ + s) * DQK;
  int d = c4 * 4;
  bf16x4 x1 = *(bf16x4*)(x + base + d);
  bf16x4 x2 = *(bf16x4*)(x + base + d + 80);
  f32x4 c1 = *(const f32x4*)(cs + (size_t)s * DQK + d);
  f32x4 s1 = *(const f32x4*)(sn + (size_t)s * DQK + d);
  f32x4 c2 = *(const f32x4*)(cs + (size_t)s * DQK + d + 80);
  f32x4 s2 = *(const f32x4*)(sn + (size_t)s * DQK + d + 80);
  bf16x4 o1, o2;
#pragma unroll
  for (int j = 0; j < 4; ++j) {
    float a = bf2f(x1[j]), b = bf2f(x2[j]);
    o1[j] = f2bf(a * c1[j] - b * s1[j]);   // d < 80:  x*cos - x[d+80]*sin
    o2[j] = f2bf(b * c2[j] + a * s2[j]);   // d >= 80: x*cos + x[d-80]*sin
  }
  *(bf16x4*)(x + base + d)      = o1;
  *(bf16x4*)(x + base + d + 80) = o2;
}

// ---------- flash attention (8 waves, 16 q-rows/wave, 2-barrier loop) ----------
// grid 1024 blocks x 512 threads; wave owns 16 q-rows; block covers 128 q-rows.
// q,k head-major [bh, s, DQK]; vt [bh, DV, s]; out token-major bf16 [8192, 2048].
__global__ __launch_bounds__(512, 4) void k_attn(const short* __restrict__ q,
                                                 const short* __restrict__ k,
                                                 const short* __restrict__ vt,
                                                 short* __restrict__ attn) {
  __shared__ short lK[64 * 160];      // 20KB, rows 320B, two-tier XOR-swizzled
  __shared__ short lV[128 * 64];      // 16KB, rows 128B, XOR-swizzled (row&7)<<4
  __shared__ short lP[8][16][40];     // 10KB, per-wave 80B rows (conflict-free)
  const int tid = threadIdx.x, lane = tid & 63, wid = tid >> 6;
  // XCD-chunked remap: each XCD gets a contiguous run of bh
  const int wg  = blockIdx.x;                                // 0..1023
  const int wg2 = (wg & 7) * 128 + (wg >> 3);
  const int bh  = wg2 >> 4, b = bh >> 4, h = bh & 15;
  const int q0  = (wg2 & 15) * 128;
  const short* Q  = q  + (size_t)bh * S_ * DQK;
  const char*  Kb = (const char*)(k + (size_t)bh * S_ * DQK);
  const char*  Vb = (const char*)(vt + (size_t)bh * DV * S_);
  const int l15 = lane & 15, l4 = lane >> 4;

  // hoist Q fragments to registers (L2-served, once per block); wave owns 16 rows
  bf16x8 qf[5];
#pragma unroll
  for (int ks = 0; ks < 5; ++ks)
    qf[ks] = *(const bf16x8*)(Q + (size_t)(q0 + wid * 16 + l15) * DQK + ks * 32 + l4 * 8);

  f32x4 acc[8] = {};
  float mrow = -1e30f, lrow = 0.f;
  const float csc = 0.07905694150420949f * 1.44269504089f; // 1/sqrt(160) * log2(e)

  // staging address precompute: K chunks wid, 8+wid, (16+wid if wid<4)
  // source pre-swizzled so LDS[row][col] = K[row][col ^ swz(row)]  (rule #21)
  int koff[3], kcolS[3];
#pragma unroll
  for (int i = 0; i < 3; ++i) {
    int c = (i < 2) ? (i * 8 + wid) : (16 + wid);   // wid<4 only for i==2
    int off = c * 1024 + lane * 16;
    int row = off / 320;
    int colB = off - row * 320;
    int g = colB >> 4;
    int colS = (g < 16) ? (colB ^ ((row & 7) << 4)) : (colB ^ ((row & 3) << 4));
    koff[i] = row;  kcolS[i] = colS;
  }
  const int vrow = lane >> 3;
  const int vcb  = (lane & 7) ^ vrow;   // V granule xor = (lane&7) ^ (row&7)

  for (int kv0 = 0; kv0 < S_; kv0 += 64) {
    // stage K tile [64][320B]: 20 chunks over 8 waves
    gload_lds16(Kb + (size_t)(kv0 + koff[0]) * 320 + kcolS[0], &lK[(wid)      * 512]);
    gload_lds16(Kb + (size_t)(kv0 + koff[1]) * 320 + kcolS[1], &lK[(8 + wid)  * 512]);
    if (wid < 4)
      gload_lds16(Kb + (size_t)(kv0 + koff[2]) * 320 + kcolS[2], &lK[(16 + wid) * 512]);
    // stage Vt tile [128][64]: 16 chunks over 8 waves
#pragma unroll
    for (int i = 0; i < 2; ++i) {
      int c = wid * 2 + i;
      gload_lds16(Vb + (size_t)(c * 8 + vrow) * (S_ * 2) + kv0 * 2 + vcb * 16, &lV[c * 512]);
    }
    __syncthreads();

    // swapped QK^T: S^T[64 kv x 16 q] per wave; kv = kj*16 + l4*4 + r, q = l15
    f32x4 sc[4] = {};
    __builtin_amdgcn_s_setprio(1);
#pragma unroll
    for (int kj = 0; kj < 4; ++kj) {
      int row = kj * 16 + l15;
      int x7 = (row & 7) << 4, x3 = (row & 3) << 4;
#pragma unroll
      for (int ks = 0; ks < 5; ++ks) {
        int colB = (ks < 4) ? ((ks * 64 + l4 * 16) ^ x7) : ((256 + l4 * 16) ^ x3);
        bf16x8 kf = *(const bf16x8*)((const char*)lK + row * 320 + colB);
        sc[kj] = MFMA_BF16(kf, qf[ks], sc[kj], 0, 0, 0);
      }
    }
    __builtin_amdgcn_s_setprio(0);

    // online softmax: per-lane q-column; in-lane max + 2 shfl; defer-max THR=8
    float mv = sc[0][0];
#pragma unroll
    for (int kj = 0; kj < 4; ++kj)
#pragma unroll
      for (int r = 0; r < 4; ++r) mv = fmaxf(mv, sc[kj][r]);
    mv = fmaxf(mv, __shfl_xor(mv, 16, 64));
    mv = fmaxf(mv, __shfl_xor(mv, 32, 64));
    float pms = mv * csc;
    if (__any(pms > mrow + 8.0f)) {
      float mn = fmaxf(mrow, pms);
      float al = exp2f(mrow - mn);
      mrow = mn; lrow *= al;
#pragma unroll
      for (int r = 0; r < 4; ++r) {
        float alr = __shfl(al, (lane & 48) | (l4 * 4 + r), 64);  // al for acc-row q
#pragma unroll
        for (int nf = 0; nf < 8; ++nf) acc[nf][r] *= alr;
      }
    }
    // P = exp2(sc*csc - m); pack pairs into dwords
    uint2 pk[4];
#pragma unroll
    for (int kj = 0; kj < 4; ++kj) {
      float p0 = exp2f(sc[kj][0] * csc - mrow);
      float p1 = exp2f(sc[kj][1] * csc - mrow);
      float p2 = exp2f(sc[kj][2] * csc - mrow);
      float p3 = exp2f(sc[kj][3] * csc - mrow);
      lrow += (p0 + p1) + (p2 + p3);
      pk[kj].x = cvt_pk_bf16(p0, p1);
      pk[kj].y = cvt_pk_bf16(p2, p3);
    }

    // PV per kv-half: write P half -> pa read -> MFMA vs lV (B-frag)
    __builtin_amdgcn_s_setprio(1);
#pragma unroll
    for (int kc = 0; kc < 2; ++kc) {
#pragma unroll
      for (int j2 = 0; j2 < 2; ++j2)
        *(uint2*)&lP[wid][l15][j2 * 16 + l4 * 4] = pk[kc * 2 + j2];
      bf16x8 pa = *(const bf16x8*)&lP[wid][l15][l4 * 8];
#pragma unroll
      for (int nf = 0; nf < 8; ++nf) {
        int row = nf * 16 + l15;
        bf16x8 vf = *(const bf16x8*)((const char*)lV + row * 128 +
                                     ((kc * 64 + l4 * 16) ^ ((row & 7) << 4)));
        acc[nf] = MFMA_BF16(pa, vf, acc[nf], 0, 0, 0);
      }
    }
    __builtin_amdgcn_s_setprio(0);
    __syncthreads();   // all waves done with lK/lV before next stage
  }

  // finalize: cross-l4 sum, invert, redistribute to acc-row layout, store
  float s = lrow;
  s += __shfl_xor(s, 16, 64);
  s += __shfl_xor(s, 32, 64);
  float inv = 1.0f / s;
  float invr[4];
#pragma unroll
  for (int r = 0; r < 4; ++r)
    invr[r] = __shfl(inv, (lane & 48) | (l4 * 4 + r), 64);
#pragma unroll
  for (int nf = 0; nf < 8; ++nf) {
    size_t col = (size_t)h * DV + nf * 16 + l15;
#pragma unroll
    for (int r = 0; r < 4; ++r) {
      int mg = q0 + wid * 16 + l4 * 4 + r;
      attn[(size_t)(b * S_ + mg) * H_ + col] = f2bf(acc[nf][r] * invr[r]);
    }
  }
}

// ---------- launcher ----------
extern "C" void kernel_launch(void* const* d_in, const int* in_sizes, int n_in,
                              void* d_out, int out_size, void* d_ws, size_t ws_size,
                              hipStream_t stream) {
  const float* hidden = (const float*)d_in[0];
  const float* cond   = (const float*)d_in[1];
  const float* cosp   = (const float*)d_in[2];
  const float* sinp   = (const float*)d_in[3];
  const float* Wq     = (const float*)d_in[4];
  const float* Wk     = (const float*)d_in[5];
  const float* Wv     = (const float*)d_in[6];
  const float* Wo     = (const float*)d_in[7];

  constexpr size_t SZ_QKIN = (size_t)MTOT * QKD * 2;     // 41,943,040
  constexpr size_t SZ_VT   = (size_t)MTOT * H_ * 2;      // 33,554,432
  constexpr size_t SZ_WBF  = (size_t)QKD * QKD * 2;      // 13,107,200
  constexpr size_t WS_NEED = SZ_QKIN * 3 + SZ_VT + SZ_WBF;
  if (ws_size < WS_NEED) return;   // defensive: never write OOB scratch

  char* ws = (char*)d_ws;
  short* qk_in = (short*)(ws);
  short* qbuf  = (short*)(ws + SZ_QKIN);
  short* kbuf  = (short*)(ws + 2 * SZ_QKIN);
  short* vtbuf = (short*)(ws + 3 * SZ_QKIN);
  short* w_bf  = (short*)(ws + 3 * SZ_QKIN + SZ_VT);
  short* attn  = qk_in;                      // alias: qk_in dead after v-projection
  float* outp  = (float*)d_out;

  k_build_qkin<<<(MTOT * QKD / 4) / 256, 256, 0, stream>>>(hidden, cond, qk_in);

  dim3 gq(QKD / 128, MTOT / 128);   // (20, 64)
  dim3 gv(H_ / 128, MTOT / 128);    // (16, 64)

  k_cvt_bf16<<<(QKD * QKD / 4) / 256, 256, 0, stream>>>(Wq, w_bf);
  k_gemm_bt<0><<<gq, 256, 0, stream>>>(qk_in, w_bf, qbuf, QKD, QKD, QKD);

  k_cvt_bf16<<<(QKD * QKD / 4) / 256, 256, 0, stream>>>(Wk, w_bf);
  k_gemm_bt<0><<<gq, 256, 0, stream>>>(qk_in, w_bf, kbuf, QKD, QKD, QKD);

  k_cvt_bf16<<<(H_ * H_ / 4) / 256, 256, 0, stream>>>(Wv, w_bf);
  k_gemm_bt<1><<<gv, 256, 0, stream>>>(qk_in, w_bf, vtbuf, H_, H_, QKD);

  k_rope<<<(B_ * NH * S_ * 20) / 256, 256, 0, stream>>>(qbuf, cosp, sinp);
  k_rope<<<(B_ * NH * S_ * 20) / 256, 256, 0, stream>>>(kbuf, cosp, sinp);

  k_attn<<<1024, 512, 0, stream>>>(qbuf, kbuf, vtbuf, attn);

  k_cvt_bf16<<<(H_ * H_ / 4) / 256, 256, 0, stream>>>(Wo, w_bf);
  k_gemm_bt<2><<<gv, 256, 0, stream>>>(attn, w_bf, outp, H_, H_, H_);
}